// Round 10
// baseline (189.936 us; speedup 1.0000x reference)
//
#include <hip/hip_runtime.h>

#define TSEQ 2048
#define DMODEL 1024
#define NHEAD 16
#define HDIM 64
#define NB 2
#define MROWS 4096   // NB*TSEQ
#define NQKV 3072    // 3*DMODEL
#define QSCALE 0.1803368801111204f  // 0.125 * log2(e): folds softmax scale+log2 into Q
#define ROPE_C (13.2877123795494f / 32.0f)  // log2(10000)/32
#define NEGINF -3.0e38f

using s16x8 = __attribute__((ext_vector_type(8))) short;
using s16x4 = __attribute__((ext_vector_type(4))) short;
using f32x4 = __attribute__((ext_vector_type(4))) float;
using u32x2 = __attribute__((ext_vector_type(2))) unsigned int;

static __device__ __forceinline__ float b2f(unsigned short u) {
  union { unsigned int i; float f; } x; x.i = ((unsigned int)u) << 16; return x.f;
}
static __device__ __forceinline__ unsigned short f2b(float f) {
  unsigned int u = __float_as_uint(f);
  u += 0x7fffu + ((u >> 16) & 1u);   // round-to-nearest-even
  return (unsigned short)(u >> 16);
}

#if __has_builtin(__builtin_amdgcn_exp2f)
#define EXP2(x) __builtin_amdgcn_exp2f(x)
#else
#define EXP2(x) exp2f(x)
#endif

// async 16B global -> LDS. LDS dest = wave-uniform base + lane*16 (m104).
typedef const __attribute__((address_space(1))) char gchar;
typedef __attribute__((address_space(3))) char lchar;
static __device__ __forceinline__ void gload_lds16(const void* g, void* l) {
  __builtin_amdgcn_global_load_lds((gchar*)g, (lchar*)l, 16, 0, 0);
}

// ---------------- 1) prep: weight transposes only (x-conv folded into qkv) ---
__global__ __launch_bounds__(256) void k_prep(const float* __restrict__ wq,
                                              short* __restrict__ wqT,
                                              const float* __restrict__ wo,
                                              short* __restrict__ woT) {
  __shared__ float tile[32][33];
  const int blk = blockIdx.x;
  const int tid = threadIdx.x;
  const float* in; short* out; int C, bx, by;
  if (blk < 3072) {
    const int l = blk; in = wq; out = wqT; C = NQKV;
    bx = l % 96; by = l / 96;
  } else {
    const int l = blk - 3072; in = wo; out = woT; C = DMODEL;
    bx = l & 31; by = l >> 5;
  }
  const int tx = tid & 31, ty4 = (tid >> 5) * 4;
#pragma unroll
  for (int i = 0; i < 4; ++i)
    tile[ty4 + i][tx] = in[(by * 32 + ty4 + i) * C + bx * 32 + tx];
  __syncthreads();
#pragma unroll
  for (int i = 0; i < 4; ++i)
    out[(bx * 32 + ty4 + i) * DMODEL + by * 32 + tx] = (short)f2b(tile[tx][ty4 + i]);
}

// ---- 2) fused QKV GEMM, T14 reg-staged single-buffer (32KB LDS) -------------
// A is read DIRECTLY from f32 x; f2b conversion happens in-register during the
// LDS write phase (bit-identical to the old prep+bf16-load path). Prefetch
// tile kt+1 into VGPRs during compute of kt; ds_write after the read-barrier.
// T1 XCD-chunked swizzle. Epilogue: per-wave LDS transpose + rope-K.
__global__ __launch_bounds__(256) void k_gemm_qkv(const float* __restrict__ X,
                                                  const short* __restrict__ BT,
                                                  short* __restrict__ Qo,
                                                  short* __restrict__ Ko,
                                                  short* __restrict__ Vt) {
  __shared__ __attribute__((aligned(16))) short As[128 * 64];   // 16 KB
  __shared__ __attribute__((aligned(16))) short Bs[128 * 64];   // 16 KB
  const int K = DMODEL;
  const int tid = threadIdx.x;
  const int wave = tid >> 6, lane = tid & 63, quad = lane >> 4, l15 = lane & 15;
  const int wm = (wave >> 1) * 64, wn = (wave & 1) * 64;
  const int bid = blockIdx.y * 24 + blockIdx.x;        // 0..767, x fastest
  const int swz = (bid & 7) * 96 + (bid >> 3);         // XCD-chunked, bijective
  const int bx = swz % 24, by = swz / 24;
  const int m0 = by * 128, n0 = bx * 128;
  f32x4 acc[4][4] = {};
  const char* Bb = (const char*)BT;
  char* AsB = (char*)As;
  char* BsB = (char*)Bs;
  int srow[4], scg[4], ssw[4];
#pragma unroll
  for (int p = 0; p < 4; ++p) {
    const int i = p * 256 + tid;
    srow[p] = i >> 3;          // 0..127
    scg[p] = i & 7;            // global 16B(bf16)/32B(f32) column, coalesced
    ssw[p] = scg[p] ^ (srow[p] & 7);   // swizzled LDS 16B column
  }
#define QLOAD(k0v)                                                            \
  do {                                                                        \
    _Pragma("unroll")                                                         \
    for (int p = 0; p < 4; ++p) {                                             \
      const long fo = (long)(m0 + srow[p]) * K + (k0v) + scg[p] * 8;          \
      fa0[p] = *(const float4*)(X + fo);                                      \
      fa1[p] = *(const float4*)(X + fo + 4);                                  \
      rb[p] = *(const f32x4*)(Bb + ((long)(n0 + srow[p]) * K + (k0v)) * 2 + scg[p] * 16); \
    }                                                                         \
  } while (0)
#define QWRITE()                                                              \
  do {                                                                        \
    _Pragma("unroll")                                                         \
    for (int p = 0; p < 4; ++p) {                                             \
      s16x8 t;                                                                \
      t[0] = (short)f2b(fa0[p].x); t[1] = (short)f2b(fa0[p].y);               \
      t[2] = (short)f2b(fa0[p].z); t[3] = (short)f2b(fa0[p].w);               \
      t[4] = (short)f2b(fa1[p].x); t[5] = (short)f2b(fa1[p].y);               \
      t[6] = (short)f2b(fa1[p].z); t[7] = (short)f2b(fa1[p].w);               \
      *(s16x8*)(AsB + srow[p] * 128 + ssw[p] * 16) = t;                       \
      *(f32x4*)(BsB + srow[p] * 128 + ssw[p] * 16) = rb[p];                   \
    }                                                                         \
  } while (0)

  float4 fa0[4], fa1[4];
  f32x4 rb[4];
  const int nK = K / 64;  // 16
  QLOAD(0);
  QWRITE();
  __syncthreads();
  for (int kt = 0; kt < nK; ++kt) {
    if (kt + 1 < nK) QLOAD((kt + 1) * 64);   // prefetch issue (hides under MFMA)
#pragma unroll
    for (int hf = 0; hf < 2; ++hf) {
      s16x8 af[4], bf[4];
#pragma unroll
      for (int i = 0; i < 4; ++i) {
        const int rowa = wm + i * 16 + l15;
        af[i] = *(const s16x8*)(AsB + rowa * 128 + (((hf * 4 + quad) ^ (rowa & 7)) * 16));
        const int rowb = wn + i * 16 + l15;
        bf[i] = *(const s16x8*)(BsB + rowb * 128 + (((hf * 4 + quad) ^ (rowb & 7)) * 16));
      }
#pragma unroll
      for (int i = 0; i < 4; ++i)
#pragma unroll
        for (int j = 0; j < 4; ++j)
          acc[i][j] = __builtin_amdgcn_mfma_f32_16x16x32_bf16(af[i], bf[j], acc[i][j], 0, 0, 0);
    }
    asm volatile("s_waitcnt lgkmcnt(0)" ::: "memory");
    __builtin_amdgcn_s_barrier();            // all reads of the buffer done
    if (kt + 1 < nK) {
      QWRITE();                              // compiler inserts vmcnt for fa/rb
      asm volatile("s_waitcnt lgkmcnt(0)" ::: "memory");
      __builtin_amdgcn_s_barrier();          // writes visible to all waves
    }
  }
#undef QLOAD
#undef QWRITE
  // ---- epilogue: per-wave LDS transpose -> coalesced 16B stores ----
  const int colbase = n0 + wn;              // multiple of 64 (one head per wave)
  const int region = colbase >> 10;         // 0=Q, 1=K, 2=V
  const int hh = (colbase & 1023) >> 6;
  const int bq = m0 >> 11;                  // batch (tile never straddles)
  const int tbase = (m0 & 2047) + wm;
  char* sw = (wave < 2) ? (AsB + wave * 8192) : (BsB + (wave - 2) * 8192);
  if (region == 2) {
#pragma unroll
    for (int i = 0; i < 4; ++i)
#pragma unroll
      for (int j = 0; j < 4; ++j) {
        const int d = j * 16 + l15;
        const int t0 = i * 16 + quad * 4;
        s16x4 w;
        w.x = (short)f2b(acc[i][j][0]);
        w.y = (short)f2b(acc[i][j][1]);
        w.z = (short)f2b(acc[i][j][2]);
        w.w = (short)f2b(acc[i][j][3]);
        *(s16x4*)(sw + d * 128 + ((((t0 >> 3) ^ (d & 7))) * 16) + (t0 & 7) * 2) = w;
      }
    short* dstv = Vt + (((long)(bq * NHEAD + hh) * HDIM) << 11);
#pragma unroll
    for (int p = 0; p < 8; ++p) {
      const int linear = p * 64 + lane;
      const int d = linear >> 3, c = linear & 7;
      const s16x8 v = *(const s16x8*)(sw + d * 128 + ((c ^ (d & 7)) * 16));
      *(s16x8*)(dstv + (((long)d) << 11) + tbase + c * 8) = v;
    }
  } else {
    if (region == 1) {
      // rope K in-register: lane holds (d, d+32) as acc[i][j], acc[i][j+2]
#pragma unroll
      for (int i = 0; i < 4; ++i)
#pragma unroll
        for (int j = 0; j < 2; ++j) {
          const int d = j * 16 + l15;                 // 0..31
          const float inv = exp2f(-(float)d * ROPE_C);
#pragma unroll
          for (int r = 0; r < 4; ++r) {
            const int t = tbase + i * 16 + quad * 4 + r;
            float sn, cs;
            __sincosf((float)t * inv, &sn, &cs);
            const float a = acc[i][j][r];
            const float bv = acc[i][j + 2][r];
            acc[i][j][r]     = a * cs - bv * sn;
            acc[i][j + 2][r] = bv * cs + a * sn;
          }
        }
    }
#pragma unroll
    for (int i = 0; i < 4; ++i)
#pragma unroll
      for (int j = 0; j < 4; ++j)
#pragma unroll
        for (int r = 0; r < 4; ++r) {
          const int row = i * 16 + quad * 4 + r;
          const int col = j * 16 + l15;
          *(short*)(sw + row * 128 + ((((col >> 3) ^ (row & 7))) * 16) + (col & 7) * 2)
              = (short)f2b(acc[i][j][r]);
        }
    short* dst = (region ? Ko : Qo) + ((long)(bq * NHEAD + hh) * TSEQ + tbase) * HDIM;
#pragma unroll
    for (int p = 0; p < 8; ++p) {
      const int linear = p * 64 + lane;
      const int r = linear >> 3, c = linear & 7;
      const s16x8 v = *(const s16x8*)(sw + r * 128 + ((c ^ (r & 7)) * 16));
      *(s16x8*)(dst + (long)r * HDIM + c * 8) = v;
    }
  }
}

// -- 3) GEMM BMx128, BK=64, LDS dbuf + counted vmcnt (round-7 verified) -------
template <int IM, bool OUT_BF16>
__global__ __launch_bounds__(256) void k_gemm(const short* __restrict__ A,
                                              const short* __restrict__ BT,
                                              void* __restrict__ Cv,
                                              int M, int N, int K) {
  static_assert(IM == 2, "vmcnt literal assumes IM==2 (6 loads/thread)");
  __shared__ __attribute__((aligned(16))) short As[2][IM * 32 * 64];
  __shared__ __attribute__((aligned(16))) short Bs[2][128 * 64];
  const int tid = threadIdx.x;
  const int wave = tid >> 6, lane = tid & 63, quad = lane >> 4, l15 = lane & 15;
  const int wm = (wave >> 1) * (IM * 16), wn = (wave & 1) * 64;
  const int nwg = gridDim.x * gridDim.y;
  const int bid = blockIdx.y * gridDim.x + blockIdx.x;
  const int swz = (bid & 7) * (nwg >> 3) + (bid >> 3);
  const int bx = swz % gridDim.x, by = swz / gridDim.x;
  const int m0 = by * (IM * 32), n0 = bx * 128;
  f32x4 acc[IM][4] = {};
  const char* Ab = (const char*)A;
  const char* Bb = (const char*)BT;
  char* AsB = (char*)As;
  char* BsB = (char*)Bs;
  int srow[4], sg[4];
#pragma unroll
  for (int p = 0; p < 4; ++p) {
    const int i = p * 256 + tid;
    srow[p] = i >> 3;
    sg[p] = (i & 7) ^ (srow[p] & 7);
  }
#define GSTAGE(k0v, buf)                                                       \
  do {                                                                         \
    _Pragma("unroll")                                                          \
    for (int p = 0; p < IM; ++p) {                                             \
      const long go = ((long)(m0 + srow[p]) * K + (k0v)) * 2 + sg[p] * 16;     \
      gload_lds16(Ab + go, AsB + (buf) * (IM * 4096) + p * 4096 + wave * 1024);\
    }                                                                          \
    _Pragma("unroll")                                                          \
    for (int p = 0; p < 4; ++p) {                                              \
      const long go = ((long)(n0 + srow[p]) * K + (k0v)) * 2 + sg[p] * 16;     \
      gload_lds16(Bb + go, BsB + (buf) * 16384 + p * 4096 + wave * 1024);      \
    }                                                                          \
  } while (0)

  const int nK = K / 64;
  GSTAGE(0, 0);
  for (int kt = 0; kt < nK; ++kt) {
    const int cur = kt & 1;
    if (kt + 1 < nK) {
      GSTAGE((kt + 1) * 64, cur ^ 1);
      asm volatile("s_waitcnt vmcnt(6)" ::: "memory");  // IM+4 = 6 in flight
    } else {
      asm volatile("s_waitcnt vmcnt(0)" ::: "memory");
    }
    __builtin_amdgcn_s_barrier();
    const char* Ac = AsB + cur * (IM * 4096);
    const char* Bc = BsB + cur * 16384;
#pragma unroll
    for (int hf = 0; hf < 2; ++hf) {
      s16x8 af[IM], bf[4];
#pragma unroll
      for (int i = 0; i < IM; ++i) {
        const int rowa = wm + i * 16 + l15;
        af[i] = *(const s16x8*)(Ac + rowa * 128 + (((hf * 4 + quad) ^ (rowa & 7)) * 16));
      }
#pragma unroll
      for (int j = 0; j < 4; ++j) {
        const int rowb = wn + j * 16 + l15;
        bf[j] = *(const s16x8*)(Bc + rowb * 128 + (((hf * 4 + quad) ^ (rowb & 7)) * 16));
      }
#pragma unroll
      for (int i = 0; i < IM; ++i)
#pragma unroll
        for (int j = 0; j < 4; ++j)
          acc[i][j] = __builtin_amdgcn_mfma_f32_16x16x32_bf16(af[i], bf[j], acc[i][j], 0, 0, 0);
    }
    asm volatile("s_waitcnt lgkmcnt(0)" ::: "memory");
    __builtin_amdgcn_s_barrier();
  }
#undef GSTAGE
  if (OUT_BF16) {
#pragma unroll
    for (int i = 0; i < IM; ++i) {
      const int row = m0 + wm + i * 16 + quad * 4;
#pragma unroll
      for (int j = 0; j < 4; ++j) {
        const int col = n0 + wn + j * 16 + l15;
#pragma unroll
        for (int r = 0; r < 4; ++r)
          ((short*)Cv)[(long)(row + r) * N + col] = (short)f2b(acc[i][j][r]);
      }
    }
  } else {
    char* sw = (char*)Bs + wave * 8192;   // Bs dead after final barrier
#pragma unroll
    for (int i = 0; i < IM; ++i)
#pragma unroll
      for (int j = 0; j < 4; ++j)
#pragma unroll
        for (int r = 0; r < 4; ++r) {
          const int row = i * 16 + quad * 4 + r;   // 0..31
          const int col = j * 16 + l15;            // 0..63
          *(float*)(sw + row * 256 + ((((col >> 2) ^ (row & 7))) * 16) + (col & 3) * 4)
              = acc[i][j][r];
        }
    float* C = (float*)Cv;
#pragma unroll
    for (int p = 0; p < 8; ++p) {
      const int linear = p * 64 + lane;
      const int r = linear >> 4, c = linear & 15;
      const f32x4 v = *(const f32x4*)(sw + r * 256 + ((c ^ (r & 7)) * 16));
      *(f32x4*)(C + (long)(m0 + wm + r) * N + n0 + wn + c * 4) = v;
    }
  }
}

// ---------------- 4) flash attention v4 (round-4/7 verified): ----------------
// BQ=128, 8 waves x 16 q-rows, LDS dbuf + counted vmcnt, ones-MFMA row-sum,
// raw v_exp_f32, setprio around MFMA, rope-K pre-applied by k_gemm_qkv.
__global__ __launch_bounds__(512) __attribute__((amdgpu_waves_per_eu(4)))
void k_attn(const short* __restrict__ Qg,
            const short* __restrict__ Kg,
            const short* __restrict__ Vg,
            short* __restrict__ O) {
  __shared__ __attribute__((aligned(16))) short Ks[2][64 * 64];
  __shared__ __attribute__((aligned(16))) short Vs[2][64 * 64];
  __shared__ __attribute__((aligned(16))) short pl[8][16 * 64];  // XOR-swizzled [q][t]
  const int bx = blockIdx.x, by = blockIdx.y;
  const int qi = ((by >> 4) & 1) ? (15 - bx) : bx;
  const int bh = by;
  const int b = bh >> 4, h = bh & 15;
  const int tid = threadIdx.x, wave = tid >> 6, lane = tid & 63;
  const int quad = lane >> 4, l15 = lane & 15;
  const char* Kb = (const char*)(Kg + (long)bh * TSEQ * HDIM);
  const char* Vb = (const char*)(Vg + (long)bh * HDIM * TSEQ);
  const short* Qb = Qg + (long)bh * TSEQ * HDIM;
  const int qr0 = qi * 128 + wave * 16;
  const s16x8 rq0 = *(const s16x8*)&Qb[(qr0 + l15) * HDIM + quad * 8];
  const s16x8 rq1 = *(const s16x8*)&Qb[(qr0 + l15) * HDIM + 32 + quad * 8];
  s16x8 aq0, aq1;
  {
    const float tf = (float)(qr0 + l15);
#pragma unroll
    for (int j = 0; j < 8; ++j) {
      const float inv = exp2f(-(float)(quad * 8 + j) * ROPE_C);
      float sn, cs;
      __sincosf(tf * inv, &sn, &cs);
      sn *= QSCALE; cs *= QSCALE;
      const float q0 = b2f((unsigned short)rq0[j]);
      const float q1 = b2f((unsigned short)rq1[j]);
      aq0[j] = (short)f2b(q0 * cs - q1 * sn);
      aq1[j] = (short)f2b(q1 * cs + q0 * sn);
    }
  }
  s16x8 ones;
#pragma unroll
  for (int j = 0; j < 8; ++j) ones[j] = (short)0x3F80;  // bf16 1.0
  f32x4 o[4] = {};          // O^T: d = hs*16 + quad*4 + r, q = l15
  f32x4 zs = {};            // ones-MFMA row-sum accumulator (cols = q = l15)
  const int kr0 = tid >> 3, kg0 = (tid & 7) ^ (kr0 & 7);
  char* KsB = (char*)Ks;
  char* VsB = (char*)Vs;
  char* plwB = (char*)pl + wave * 2048;
  const int ldsw = wave * 1024;  // + lane*16 by HW

#define STAGE(kjv, buf)                                                     \
  do {                                                                      \
    gload_lds16(Kb + (kjv) * 8192 + (kr0 * 8 + kg0) * 16,                   \
                KsB + (buf) * 8192 + ldsw);                                 \
    gload_lds16(Vb + (kjv) * 128 + kr0 * (TSEQ * 2) + kg0 * 16,             \
                VsB + (buf) * 8192 + ldsw);                                 \
  } while (0)

  STAGE(0, 0);

  const int kjmax = 2 * qi + 1;      // last K-tile this block needs
  const int kjd = qr0 >> 6;          // this wave's diagonal tile (skip beyond)
  for (int kj = 0; kj <= kjmax; ++kj) {
    const int cur = kj & 1;
    if (kj < kjmax) {
      STAGE(kj + 1, cur ^ 1);
      asm volatile("s_waitcnt vmcnt(2)" ::: "memory");
    } else {
      asm volatile("s_waitcnt vmcnt(0)" ::: "memory");
    }
    __builtin_amdgcn_s_barrier();    // publish buf[cur]
    if (kj <= kjd) {
      const char* kb = KsB + cur * 8192;
      const char* vb = VsB + cur * 8192;
      f32x4 s[4];
      __builtin_amdgcn_s_setprio(1);
#pragma unroll
      for (int j2 = 0; j2 < 4; ++j2) {
        const int row = j2 * 16 + l15;
        const s16x8 k0 = *(const s16x8*)(kb + row * 128 + ((quad ^ (row & 7)) * 16));
        const s16x8 k1 = *(const s16x8*)(kb + row * 128 + (((4 + quad) ^ (row & 7)) * 16));
        f32x4 z = {};
        z = __builtin_amdgcn_mfma_f32_16x16x32_bf16(k0, aq0, z, 0, 0, 0);
        z = __builtin_amdgcn_mfma_f32_16x16x32_bf16(k1, aq1, z, 0, 0, 0);
        s[j2] = z;
      }
      __builtin_amdgcn_s_setprio(0);
      if (kj == kjd) {
        const int qloc = (qr0 & 63) + l15;
#pragma unroll
        for (int j2 = 0; j2 < 4; ++j2)
#pragma unroll
          for (int r = 0; r < 4; ++r)
            if (j2 * 16 + quad * 4 + r > qloc) s[j2][r] = NEGINF;
      }
#pragma unroll
      for (int j2 = 0; j2 < 4; ++j2) {
        const unsigned int u0 = __float_as_uint(EXP2(s[j2][0])) & 0xffff0000u;
        const unsigned int u1 = __float_as_uint(EXP2(s[j2][1])) & 0xffff0000u;
        const unsigned int u2 = __float_as_uint(EXP2(s[j2][2])) & 0xffff0000u;
        const unsigned int u3 = __float_as_uint(EXP2(s[j2][3])) & 0xffff0000u;
        u32x2 w;
        w.x = (u0 >> 16) | u1;
        w.y = (u2 >> 16) | u3;
        const int t0 = j2 * 16 + quad * 4;
        *(u32x2*)(plwB + l15 * 128 + (((t0 >> 3) ^ (l15 & 7)) * 16) + (quad & 1) * 8) = w;
      }
      const s16x8 bp0 = *(const s16x8*)(plwB + l15 * 128 + ((quad ^ (l15 & 7)) * 16));
      const s16x8 bp1 = *(const s16x8*)(plwB + l15 * 128 + (((4 + quad) ^ (l15 & 7)) * 16));
      __builtin_amdgcn_s_setprio(1);
      zs = __builtin_amdgcn_mfma_f32_16x16x32_bf16(ones, bp0, zs, 0, 0, 0);
      zs = __builtin_amdgcn_mfma_f32_16x16x32_bf16(ones, bp1, zs, 0, 0, 0);
#pragma unroll
      for (int hs = 0; hs < 4; ++hs) {
        const int d = hs * 16 + l15;
        const s16x8 av0 = *(const s16x8*)(vb + d * 128 + ((quad ^ (d & 7)) * 16));
        const s16x8 av1 = *(const s16x8*)(vb + d * 128 + (((4 + quad) ^ (d & 7)) * 16));
        o[hs] = __builtin_amdgcn_mfma_f32_16x16x32_bf16(av0, bp0, o[hs], 0, 0, 0);
        o[hs] = __builtin_amdgcn_mfma_f32_16x16x32_bf16(av1, bp1, o[hs], 0, 0, 0);
      }
      __builtin_amdgcn_s_setprio(0);
    }
    asm volatile("s_waitcnt lgkmcnt(0)" ::: "memory");
    __builtin_amdgcn_s_barrier();    // all reads of buf[cur] done
  }
#undef STAGE
  const float rinv = 1.0f / zs[0];   // all 4 rows identical = sum_t P[q=l15][t]
  const int t = qr0 + l15;
  short* Orow = O + (long)(b * TSEQ + t) * DMODEL + h * HDIM + quad * 4;
#pragma unroll
  for (int hs = 0; hs < 4; ++hs) {
    s16x4 w;
    w.x = (short)f2b(o[hs][0] * rinv);
    w.y = (short)f2b(o[hs][1] * rinv);
    w.z = (short)f2b(o[hs][2] * rinv);
    w.w = (short)f2b(o[hs][3] * rinv);
    *(s16x4*)(Orow + hs * 16) = w;  // 8B store, d consecutive
  }
}

// ---------------- launch ----------------
extern "C" void kernel_launch(void* const* d_in, const int* in_sizes, int n_in,
                              void* d_out, int out_size, void* d_ws, size_t ws_size,
                              hipStream_t stream) {
  const float* x = (const float*)d_in[0];      // [2,2048,1024]
  const float* w_qkv = (const float*)d_in[1];  // [1024,3072]
  const float* w_out = (const float*)d_in[2];  // [1024,1024]
  float* out = (float*)d_out;                  // [2,2048,1024]
  char* ws = (char*)d_ws;

  short* wqkvT = (short*)(ws);                        //  6 MiB
  short* woutT = (short*)(ws + (6ll << 20));          //  2 MiB
  short* Qb    = (short*)(ws + (8ll << 20));          //  8 MiB
  short* Kb    = (short*)(ws + (16ll << 20));         //  8 MiB
  short* Vt    = (short*)(ws + (24ll << 20));         //  8 MiB
  short* Ob    = (short*)(ws + (32ll << 20));         //  8 MiB  (total 40 MiB)

  k_prep<<<dim3(4096), dim3(256), 0, stream>>>(w_qkv, wqkvT, w_out, woutT);
  k_gemm_qkv<<<dim3(NQKV / 128, MROWS / 128), dim3(256), 0, stream>>>(
      x, wqkvT, Qb, Kb, Vt);
  k_attn<<<dim3(TSEQ / 128, NB * NHEAD), dim3(512), 0, stream>>>(Qb, Kb, Vt, Ob);
  k_gemm<2, false><<<dim3(DMODEL / 128, MROWS / 64), dim3(256), 0, stream>>>(
      Ob, woutT, (void*)out, MROWS, DMODEL, DMODEL);
}

// Round 11
// 175.056 us; speedup vs baseline: 1.0850x; 1.0850x over previous
//
#include <hip/hip_runtime.h>

#define TSEQ 2048
#define DMODEL 1024
#define NHEAD 16
#define HDIM 64
#define NB 2
#define MROWS 4096   // NB*TSEQ
#define NQKV 3072    // 3*DMODEL
#define QSCALE 0.1803368801111204f  // 0.125 * log2(e): folds softmax scale+log2 into Q
#define ROPE_C (13.2877123795494f / 32.0f)  // log2(10000)/32
#define NEGINF -3.0e38f

using s16x8 = __attribute__((ext_vector_type(8))) short;
using s16x4 = __attribute__((ext_vector_type(4))) short;
using f32x4 = __attribute__((ext_vector_type(4))) float;
using u32x2 = __attribute__((ext_vector_type(2))) unsigned int;

static __device__ __forceinline__ float b2f(unsigned short u) {
  union { unsigned int i; float f; } x; x.i = ((unsigned int)u) << 16; return x.f;
}
static __device__ __forceinline__ unsigned short f2b(float f) {
  unsigned int u = __float_as_uint(f);
  u += 0x7fffu + ((u >> 16) & 1u);   // round-to-nearest-even
  return (unsigned short)(u >> 16);
}

#if __has_builtin(__builtin_amdgcn_exp2f)
#define EXP2(x) __builtin_amdgcn_exp2f(x)
#else
#define EXP2(x) exp2f(x)
#endif

// async 16B global -> LDS. LDS dest = wave-uniform base + lane*16 (m104).
typedef const __attribute__((address_space(1))) char gchar;
typedef __attribute__((address_space(3))) char lchar;
static __device__ __forceinline__ void gload_lds16(const void* g, void* l) {
  __builtin_amdgcn_global_load_lds((gchar*)g, (lchar*)l, 16, 0, 0);
}

// ---------------- 1) merged prep: x->bf16 convert + both weight transposes ----
// x-conv stays HERE: folding it into qkv replicates the conversion 24x (one
// per n-column block) and doubles the A-load bytes on qkv's critical path
// (round-10 regression: 47->82 us). Prep does it ONCE at HBM bandwidth.
__global__ __launch_bounds__(256) void k_prep(const float* __restrict__ x,
                                              short* __restrict__ xb,
                                              const float* __restrict__ wq,
                                              short* __restrict__ wqT,
                                              const float* __restrict__ wo,
                                              short* __restrict__ woT) {
  __shared__ float tile[32][33];
  const int blk = blockIdx.x;
  const int tid = threadIdx.x;
  if (blk < 4096) {
    const int i = blk * 256 + tid;
    const float4 v = ((const float4*)x)[i];
    s16x4 o;
    o.x = (short)f2b(v.x); o.y = (short)f2b(v.y);
    o.z = (short)f2b(v.z); o.w = (short)f2b(v.w);
    ((s16x4*)xb)[i] = o;
    return;
  }
  const float* in; short* out; int C, bx, by;
  if (blk < 7168) {
    const int l = blk - 4096; in = wq; out = wqT; C = NQKV;
    bx = l % 96; by = l / 96;
  } else {
    const int l = blk - 7168; in = wo; out = woT; C = DMODEL;
    bx = l & 31; by = l >> 5;
  }
  const int tx = tid & 31, ty4 = (tid >> 5) * 4;
#pragma unroll
  for (int i = 0; i < 4; ++i)
    tile[ty4 + i][tx] = in[(by * 32 + ty4 + i) * C + bx * 32 + tx];
  __syncthreads();
#pragma unroll
  for (int i = 0; i < 4; ++i)
    out[(bx * 32 + ty4 + i) * DMODEL + by * 32 + tx] = (short)f2b(tile[tx][ty4 + i]);
}

// ---- 2) fused QKV GEMM, T14 reg-staged single-buffer (32KB LDS, 3 blk/CU) ---
// Session-best variant (round 7, 47.2 us). Prefetch tile kt+1 into VGPRs
// during compute of kt; ds_write after the read-barrier. T1 XCD-chunked
// swizzle. Epilogue: per-wave LDS transpose -> coalesced stores; rope-K fused.
__global__ __launch_bounds__(256) void k_gemm_qkv(const short* __restrict__ A,
                                                  const short* __restrict__ BT,
                                                  short* __restrict__ Qo,
                                                  short* __restrict__ Ko,
                                                  short* __restrict__ Vt) {
  __shared__ __attribute__((aligned(16))) short As[128 * 64];   // 16 KB
  __shared__ __attribute__((aligned(16))) short Bs[128 * 64];   // 16 KB
  const int K = DMODEL;
  const int tid = threadIdx.x;
  const int wave = tid >> 6, lane = tid & 63, quad = lane >> 4, l15 = lane & 15;
  const int wm = (wave >> 1) * 64, wn = (wave & 1) * 64;
  const int bid = blockIdx.y * 24 + blockIdx.x;        // 0..767, x fastest
  const int swz = (bid & 7) * 96 + (bid >> 3);         // XCD-chunked, bijective
  const int bx = swz % 24, by = swz / 24;
  const int m0 = by * 128, n0 = bx * 128;
  f32x4 acc[4][4] = {};
  const char* Ab = (const char*)A;
  const char* Bb = (const char*)BT;
  char* AsB = (char*)As;
  char* BsB = (char*)Bs;
  int srow[4], scg[4], ssw[4];
#pragma unroll
  for (int p = 0; p < 4; ++p) {
    const int i = p * 256 + tid;
    srow[p] = i >> 3;          // 0..127
    scg[p] = i & 7;            // global 16B column (linear, coalesced)
    ssw[p] = scg[p] ^ (srow[p] & 7);   // swizzled LDS 16B column
  }
#define QLOAD(k0v)                                                            \
  do {                                                                        \
    _Pragma("unroll")                                                         \
    for (int p = 0; p < 4; ++p) {                                             \
      ra[p] = *(const f32x4*)(Ab + ((long)(m0 + srow[p]) * K + (k0v)) * 2 + scg[p] * 16); \
      rb[p] = *(const f32x4*)(Bb + ((long)(n0 + srow[p]) * K + (k0v)) * 2 + scg[p] * 16); \
    }                                                                         \
  } while (0)
#define QWRITE()                                                              \
  do {                                                                        \
    _Pragma("unroll")                                                         \
    for (int p = 0; p < 4; ++p) {                                             \
      *(f32x4*)(AsB + srow[p] * 128 + ssw[p] * 16) = ra[p];                   \
      *(f32x4*)(BsB + srow[p] * 128 + ssw[p] * 16) = rb[p];                   \
    }                                                                         \
  } while (0)

  f32x4 ra[4], rb[4];
  const int nK = K / 64;  // 16
  QLOAD(0);
  QWRITE();
  __syncthreads();
  for (int kt = 0; kt < nK; ++kt) {
    if (kt + 1 < nK) QLOAD((kt + 1) * 64);   // prefetch issue (hides under MFMA)
#pragma unroll
    for (int hf = 0; hf < 2; ++hf) {
      s16x8 af[4], bf[4];
#pragma unroll
      for (int i = 0; i < 4; ++i) {
        const int rowa = wm + i * 16 + l15;
        af[i] = *(const s16x8*)(AsB + rowa * 128 + (((hf * 4 + quad) ^ (rowa & 7)) * 16));
        const int rowb = wn + i * 16 + l15;
        bf[i] = *(const s16x8*)(BsB + rowb * 128 + (((hf * 4 + quad) ^ (rowb & 7)) * 16));
      }
#pragma unroll
      for (int i = 0; i < 4; ++i)
#pragma unroll
        for (int j = 0; j < 4; ++j)
          acc[i][j] = __builtin_amdgcn_mfma_f32_16x16x32_bf16(af[i], bf[j], acc[i][j], 0, 0, 0);
    }
    asm volatile("s_waitcnt lgkmcnt(0)" ::: "memory");
    __builtin_amdgcn_s_barrier();            // all reads of the buffer done
    if (kt + 1 < nK) {
      QWRITE();                              // compiler inserts vmcnt for ra/rb
      asm volatile("s_waitcnt lgkmcnt(0)" ::: "memory");
      __builtin_amdgcn_s_barrier();          // writes visible to all waves
    }
  }
#undef QLOAD
#undef QWRITE
  // ---- epilogue: per-wave LDS transpose -> coalesced 16B stores ----
  const int colbase = n0 + wn;              // multiple of 64 (one head per wave)
  const int region = colbase >> 10;         // 0=Q, 1=K, 2=V
  const int hh = (colbase & 1023) >> 6;
  const int bq = m0 >> 11;                  // batch (tile never straddles)
  const int tbase = (m0 & 2047) + wm;
  // 8KB wave-private scratch: waves 0,1 in As; waves 2,3 in Bs (both dead)
  char* sw = (wave < 2) ? (AsB + wave * 8192) : (BsB + (wave - 2) * 8192);
  if (region == 2) {
    // V: scratch [d 0..63][t 0..63] bf16; lane's 4 acc values are t-contiguous
#pragma unroll
    for (int i = 0; i < 4; ++i)
#pragma unroll
      for (int j = 0; j < 4; ++j) {
        const int d = j * 16 + l15;
        const int t0 = i * 16 + quad * 4;
        s16x4 w;
        w.x = (short)f2b(acc[i][j][0]);
        w.y = (short)f2b(acc[i][j][1]);
        w.z = (short)f2b(acc[i][j][2]);
        w.w = (short)f2b(acc[i][j][3]);
        *(s16x4*)(sw + d * 128 + ((((t0 >> 3) ^ (d & 7))) * 16) + (t0 & 7) * 2) = w;
      }
    short* dstv = Vt + (((long)(bq * NHEAD + hh) * HDIM) << 11);
#pragma unroll
    for (int p = 0; p < 8; ++p) {
      const int linear = p * 64 + lane;
      const int d = linear >> 3, c = linear & 7;
      const s16x8 v = *(const s16x8*)(sw + d * 128 + ((c ^ (d & 7)) * 16));
      *(s16x8*)(dstv + (((long)d) << 11) + tbase + c * 8) = v;
    }
  } else {
    if (region == 1) {
      // rope K in-register: lane holds (d, d+32) as acc[i][j], acc[i][j+2]
#pragma unroll
      for (int i = 0; i < 4; ++i)
#pragma unroll
        for (int j = 0; j < 2; ++j) {
          const int d = j * 16 + l15;                 // 0..31
          const float inv = exp2f(-(float)d * ROPE_C);
#pragma unroll
          for (int r = 0; r < 4; ++r) {
            const int t = tbase + i * 16 + quad * 4 + r;
            float sn, cs;
            __sincosf((float)t * inv, &sn, &cs);
            const float a = acc[i][j][r];
            const float bv = acc[i][j + 2][r];
            acc[i][j][r]     = a * cs - bv * sn;
            acc[i][j + 2][r] = bv * cs + a * sn;
          }
        }
    }
    // Q/K: scratch [t 0..63][d 0..63] bf16
#pragma unroll
    for (int i = 0; i < 4; ++i)
#pragma unroll
      for (int j = 0; j < 4; ++j)
#pragma unroll
        for (int r = 0; r < 4; ++r) {
          const int row = i * 16 + quad * 4 + r;
          const int col = j * 16 + l15;
          *(short*)(sw + row * 128 + ((((col >> 3) ^ (row & 7))) * 16) + (col & 7) * 2)
              = (short)f2b(acc[i][j][r]);
        }
    short* dst = (region ? Ko : Qo) + ((long)(bq * NHEAD + hh) * TSEQ + tbase) * HDIM;
#pragma unroll
    for (int p = 0; p < 8; ++p) {
      const int linear = p * 64 + lane;
      const int r = linear >> 3, c = linear & 7;
      const s16x8 v = *(const s16x8*)(sw + r * 128 + ((c ^ (r & 7)) * 16));
      *(s16x8*)(dst + (long)r * HDIM + c * 8) = v;
    }
  }
}

// -- 3) GEMM BMx128, BK=64, LDS dbuf + counted vmcnt: C = A[M][K] * BT[N][K]^T
// T1: XCD-chunked blockIdx swizzle (grid must be divisible by 8).
// 512 blocks = 2/CU; round-8 showed the 256-block 128^2 clone regresses
// (1 block/CU = 1 wave/SIMD, nothing hides the barriers). Keep IM=2.
template <int IM, bool OUT_BF16>
__global__ __launch_bounds__(256) void k_gemm(const short* __restrict__ A,
                                              const short* __restrict__ BT,
                                              void* __restrict__ Cv,
                                              int M, int N, int K) {
  static_assert(IM == 2, "vmcnt literal assumes IM==2 (6 loads/thread)");
  __shared__ __attribute__((aligned(16))) short As[2][IM * 32 * 64];
  __shared__ __attribute__((aligned(16))) short Bs[2][128 * 64];
  const int tid = threadIdx.x;
  const int wave = tid >> 6, lane = tid & 63, quad = lane >> 4, l15 = lane & 15;
  const int wm = (wave >> 1) * (IM * 16), wn = (wave & 1) * 64;
  const int nwg = gridDim.x * gridDim.y;
  const int bid = blockIdx.y * gridDim.x + blockIdx.x;
  const int swz = (bid & 7) * (nwg >> 3) + (bid >> 3);
  const int bx = swz % gridDim.x, by = swz / gridDim.x;
  const int m0 = by * (IM * 32), n0 = bx * 128;
  f32x4 acc[IM][4] = {};
  const char* Ab = (const char*)A;
  const char* Bb = (const char*)BT;
  char* AsB = (char*)As;
  char* BsB = (char*)Bs;
  int srow[4], sg[4];
#pragma unroll
  for (int p = 0; p < 4; ++p) {
    const int i = p * 256 + tid;
    srow[p] = i >> 3;
    sg[p] = (i & 7) ^ (srow[p] & 7);
  }
#define GSTAGE(k0v, buf)                                                       \
  do {                                                                         \
    _Pragma("unroll")                                                          \
    for (int p = 0; p < IM; ++p) {                                             \
      const long go = ((long)(m0 + srow[p]) * K + (k0v)) * 2 + sg[p] * 16;     \
      gload_lds16(Ab + go, AsB + (buf) * (IM * 4096) + p * 4096 + wave * 1024);\
    }                                                                          \
    _Pragma("unroll")                                                          \
    for (int p = 0; p < 4; ++p) {                                              \
      const long go = ((long)(n0 + srow[p]) * K + (k0v)) * 2 + sg[p] * 16;     \
      gload_lds16(Bb + go, BsB + (buf) * 16384 + p * 4096 + wave * 1024);      \
    }                                                                          \
  } while (0)

  const int nK = K / 64;
  GSTAGE(0, 0);
  for (int kt = 0; kt < nK; ++kt) {
    const int cur = kt & 1;
    if (kt + 1 < nK) {
      GSTAGE((kt + 1) * 64, cur ^ 1);
      asm volatile("s_waitcnt vmcnt(6)" ::: "memory");  // IM+4 = 6 in flight
    } else {
      asm volatile("s_waitcnt vmcnt(0)" ::: "memory");
    }
    __builtin_amdgcn_s_barrier();
    const char* Ac = AsB + cur * (IM * 4096);
    const char* Bc = BsB + cur * 16384;
#pragma unroll
    for (int hf = 0; hf < 2; ++hf) {
      s16x8 af[IM], bf[4];
#pragma unroll
      for (int i = 0; i < IM; ++i) {
        const int rowa = wm + i * 16 + l15;
        af[i] = *(const s16x8*)(Ac + rowa * 128 + (((hf * 4 + quad) ^ (rowa & 7)) * 16));
      }
#pragma unroll
      for (int j = 0; j < 4; ++j) {
        const int rowb = wn + j * 16 + l15;
        bf[j] = *(const s16x8*)(Bc + rowb * 128 + (((hf * 4 + quad) ^ (rowb & 7)) * 16));
      }
#pragma unroll
      for (int i = 0; i < IM; ++i)
#pragma unroll
        for (int j = 0; j < 4; ++j)
          acc[i][j] = __builtin_amdgcn_mfma_f32_16x16x32_bf16(af[i], bf[j], acc[i][j], 0, 0, 0);
    }
    asm volatile("s_waitcnt lgkmcnt(0)" ::: "memory");
    __builtin_amdgcn_s_barrier();
  }
#undef GSTAGE
  if (OUT_BF16) {
#pragma unroll
    for (int i = 0; i < IM; ++i) {
      const int row = m0 + wm + i * 16 + quad * 4;
#pragma unroll
      for (int j = 0; j < 4; ++j) {
        const int col = n0 + wn + j * 16 + l15;
#pragma unroll
        for (int r = 0; r < 4; ++r)
          ((short*)Cv)[(long)(row + r) * N + col] = (short)f2b(acc[i][j][r]);
      }
    }
  } else {
    // f32 epilogue via per-wave 8KB LDS scratch [32 r][64 c], coalesced stores
    char* sw = (char*)Bs + wave * 8192;   // Bs dead after final barrier
#pragma unroll
    for (int i = 0; i < IM; ++i)
#pragma unroll
      for (int j = 0; j < 4; ++j)
#pragma unroll
        for (int r = 0; r < 4; ++r) {
          const int row = i * 16 + quad * 4 + r;   // 0..31
          const int col = j * 16 + l15;            // 0..63
          *(float*)(sw + row * 256 + ((((col >> 2) ^ (row & 7))) * 16) + (col & 3) * 4)
              = acc[i][j][r];
        }
    float* C = (float*)Cv;
#pragma unroll
    for (int p = 0; p < 8; ++p) {
      const int linear = p * 64 + lane;
      const int r = linear >> 4, c = linear & 15;
      const f32x4 v = *(const f32x4*)(sw + r * 256 + ((c ^ (r & 7)) * 16));
      *(f32x4*)(C + (long)(m0 + wm + r) * N + n0 + wn + c * 4) = v;
    }
  }
}

// ---------------- 4) flash attention v4 (round-4/7 verified local optimum): --
// BQ=128, 8 waves x 16 q-rows, LDS dbuf + counted vmcnt(2), ones-MFMA row-sum,
// raw v_exp_f32, setprio around MFMA, rope-K pre-applied by k_gemm_qkv.
// v5 (4wx32q: 52.4) and v6 (32x32 MFMA: 60) both lost to this structure.
__global__ __launch_bounds__(512) __attribute__((amdgpu_waves_per_eu(4)))
void k_attn(const short* __restrict__ Qg,
            const short* __restrict__ Kg,
            const short* __restrict__ Vg,
            short* __restrict__ O) {
  __shared__ __attribute__((aligned(16))) short Ks[2][64 * 64];
  __shared__ __attribute__((aligned(16))) short Vs[2][64 * 64];
  __shared__ __attribute__((aligned(16))) short pl[8][16 * 64];  // XOR-swizzled [q][t]
  const int bx = blockIdx.x, by = blockIdx.y;
  const int qi = ((by >> 4) & 1) ? (15 - bx) : bx;
  const int bh = by;
  const int b = bh >> 4, h = bh & 15;
  const int tid = threadIdx.x, wave = tid >> 6, lane = tid & 63;
  const int quad = lane >> 4, l15 = lane & 15;
  const char* Kb = (const char*)(Kg + (long)bh * TSEQ * HDIM);
  const char* Vb = (const char*)(Vg + (long)bh * HDIM * TSEQ);
  const short* Qb = Qg + (long)bh * TSEQ * HDIM;
  const int qr0 = qi * 128 + wave * 16;
  const s16x8 rq0 = *(const s16x8*)&Qb[(qr0 + l15) * HDIM + quad * 8];
  const s16x8 rq1 = *(const s16x8*)&Qb[(qr0 + l15) * HDIM + 32 + quad * 8];
  s16x8 aq0, aq1;
  {
    const float tf = (float)(qr0 + l15);
#pragma unroll
    for (int j = 0; j < 8; ++j) {
      const float inv = exp2f(-(float)(quad * 8 + j) * ROPE_C);
      float sn, cs;
      __sincosf(tf * inv, &sn, &cs);
      sn *= QSCALE; cs *= QSCALE;
      const float q0 = b2f((unsigned short)rq0[j]);
      const float q1 = b2f((unsigned short)rq1[j]);
      aq0[j] = (short)f2b(q0 * cs - q1 * sn);
      aq1[j] = (short)f2b(q1 * cs + q0 * sn);
    }
  }
  s16x8 ones;
#pragma unroll
  for (int j = 0; j < 8; ++j) ones[j] = (short)0x3F80;  // bf16 1.0
  f32x4 o[4] = {};          // O^T: d = hs*16 + quad*4 + r, q = l15
  f32x4 zs = {};            // ones-MFMA row-sum accumulator (cols = q = l15)
  const int kr0 = tid >> 3, kg0 = (tid & 7) ^ (kr0 & 7);
  char* KsB = (char*)Ks;
  char* VsB = (char*)Vs;
  char* plwB = (char*)pl + wave * 2048;
  const int ldsw = wave * 1024;  // + lane*16 by HW

#define STAGE(kjv, buf)                                                     \
  do {                                                                      \
    gload_lds16(Kb + (kjv) * 8192 + (kr0 * 8 + kg0) * 16,                   \
                KsB + (buf) * 8192 + ldsw);                                 \
    gload_lds16(Vb + (kjv) * 128 + kr0 * (TSEQ * 2) + kg0 * 16,             \
                VsB + (buf) * 8192 + ldsw);                                 \
  } while (0)

  STAGE(0, 0);

  const int kjmax = 2 * qi + 1;      // last K-tile this block needs
  const int kjd = qr0 >> 6;          // this wave's diagonal tile (skip beyond)
  for (int kj = 0; kj <= kjmax; ++kj) {
    const int cur = kj & 1;
    if (kj < kjmax) {
      STAGE(kj + 1, cur ^ 1);
      asm volatile("s_waitcnt vmcnt(2)" ::: "memory");
    } else {
      asm volatile("s_waitcnt vmcnt(0)" ::: "memory");
    }
    __builtin_amdgcn_s_barrier();    // publish buf[cur]
    if (kj <= kjd) {
      const char* kb = KsB + cur * 8192;
      const char* vb = VsB + cur * 8192;
      f32x4 s[4];
      __builtin_amdgcn_s_setprio(1);
#pragma unroll
      for (int j2 = 0; j2 < 4; ++j2) {
        const int row = j2 * 16 + l15;
        const s16x8 k0 = *(const s16x8*)(kb + row * 128 + ((quad ^ (row & 7)) * 16));
        const s16x8 k1 = *(const s16x8*)(kb + row * 128 + (((4 + quad) ^ (row & 7)) * 16));
        f32x4 z = {};
        z = __builtin_amdgcn_mfma_f32_16x16x32_bf16(k0, aq0, z, 0, 0, 0);
        z = __builtin_amdgcn_mfma_f32_16x16x32_bf16(k1, aq1, z, 0, 0, 0);
        s[j2] = z;
      }
      __builtin_amdgcn_s_setprio(0);
      if (kj == kjd) {
        const int qloc = (qr0 & 63) + l15;
#pragma unroll
        for (int j2 = 0; j2 < 4; ++j2)
#pragma unroll
          for (int r = 0; r < 4; ++r)
            if (j2 * 16 + quad * 4 + r > qloc) s[j2][r] = NEGINF;
      }
#pragma unroll
      for (int j2 = 0; j2 < 4; ++j2) {
        const unsigned int u0 = __float_as_uint(EXP2(s[j2][0])) & 0xffff0000u;
        const unsigned int u1 = __float_as_uint(EXP2(s[j2][1])) & 0xffff0000u;
        const unsigned int u2 = __float_as_uint(EXP2(s[j2][2])) & 0xffff0000u;
        const unsigned int u3 = __float_as_uint(EXP2(s[j2][3])) & 0xffff0000u;
        u32x2 w;
        w.x = (u0 >> 16) | u1;
        w.y = (u2 >> 16) | u3;
        const int t0 = j2 * 16 + quad * 4;
        *(u32x2*)(plwB + l15 * 128 + (((t0 >> 3) ^ (l15 & 7)) * 16) + (quad & 1) * 8) = w;
      }
      const s16x8 bp0 = *(const s16x8*)(plwB + l15 * 128 + ((quad ^ (l15 & 7)) * 16));
      const s16x8 bp1 = *(const s16x8*)(plwB + l15 * 128 + (((4 + quad) ^ (l15 & 7)) * 16));
      __builtin_amdgcn_s_setprio(1);
      zs = __builtin_amdgcn_mfma_f32_16x16x32_bf16(ones, bp0, zs, 0, 0, 0);
      zs = __builtin_amdgcn_mfma_f32_16x16x32_bf16(ones, bp1, zs, 0, 0, 0);
#pragma unroll
      for (int hs = 0; hs < 4; ++hs) {
        const int d = hs * 16 + l15;
        const s16x8 av0 = *(const s16x8*)(vb + d * 128 + ((quad ^ (d & 7)) * 16));
        const s16x8 av1 = *(const s16x8*)(vb + d * 128 + (((4 + quad) ^ (d & 7)) * 16));
        o[hs] = __builtin_amdgcn_mfma_f32_16x16x32_bf16(av0, bp0, o[hs], 0, 0, 0);
        o[hs] = __builtin_amdgcn_mfma_f32_16x16x32_bf16(av1, bp1, o[hs], 0, 0, 0);
      }
      __builtin_amdgcn_s_setprio(0);
    }
    asm volatile("s_waitcnt lgkmcnt(0)" ::: "memory");
    __builtin_amdgcn_s_barrier();    // all reads of buf[cur] done
  }
#undef STAGE
  const float rinv = 1.0f / zs[0];   // all 4 rows identical = sum_t P[q=l15][t]
  const int t = qr0 + l15;
  short* Orow = O + (long)(b * TSEQ + t) * DMODEL + h * HDIM + quad * 4;
#pragma unroll
  for (int hs = 0; hs < 4; ++hs) {
    s16x4 w;
    w.x = (short)f2b(o[hs][0] * rinv);
    w.y = (short)f2b(o[hs][1] * rinv);
    w.z = (short)f2b(o[hs][2] * rinv);
    w.w = (short)f2b(o[hs][3] * rinv);
    *(s16x4*)(Orow + hs * 16) = w;  // 8B store, d consecutive
  }
}

// ---------------- launch ----------------
extern "C" void kernel_launch(void* const* d_in, const int* in_sizes, int n_in,
                              void* d_out, int out_size, void* d_ws, size_t ws_size,
                              hipStream_t stream) {
  const float* x = (const float*)d_in[0];      // [2,2048,1024]
  const float* w_qkv = (const float*)d_in[1];  // [1024,3072]
  const float* w_out = (const float*)d_in[2];  // [1024,1024]
  float* out = (float*)d_out;                  // [2,2048,1024]
  char* ws = (char*)d_ws;

  short* xb    = (short*)(ws);                        //  8 MiB
  short* wqkvT = (short*)(ws + (8ll << 20));          //  6 MiB
  short* woutT = (short*)(ws + (14ll << 20));         //  2 MiB
  short* Qb    = (short*)(ws + (16ll << 20));         //  8 MiB
  short* Kb    = (short*)(ws + (24ll << 20));         //  8 MiB
  short* Vt    = (short*)(ws + (32ll << 20));         //  8 MiB
  short* Ob    = (short*)(ws + (40ll << 20));         //  8 MiB  (total 48 MiB)

  k_prep<<<dim3(8192), dim3(256), 0, stream>>>(x, xb, w_qkv, wqkvT, w_out, woutT);
  k_gemm_qkv<<<dim3(NQKV / 128, MROWS / 128), dim3(256), 0, stream>>>(
      xb, wqkvT, Qb, Kb, Vt);
  k_attn<<<dim3(TSEQ / 128, NB * NHEAD), dim3(512), 0, stream>>>(Qb, Kb, Vt, Ob);
  k_gemm<2, false><<<dim3(DMODEL / 128, MROWS / 64), dim3(256), 0, stream>>>(
      Ob, woutT, (void*)out, MROWS, DMODEL, DMODEL);
}

// Round 12
// 168.842 us; speedup vs baseline: 1.1249x; 1.0368x over previous
//
#include <hip/hip_runtime.h>

#define TSEQ 2048
#define DMODEL 1024
#define NHEAD 16
#define HDIM 64
#define NB 2
#define MROWS 4096   // NB*TSEQ
#define NQKV 3072    // 3*DMODEL
#define QSCALE 0.1803368801111204f  // 0.125 * log2(e): folds softmax scale+log2 into Q
#define ROPE_C (13.2877123795494f / 32.0f)  // log2(10000)/32
#define NEGINF -3.0e38f

using s16x8 = __attribute__((ext_vector_type(8))) short;
using s16x4 = __attribute__((ext_vector_type(4))) short;
using f32x4 = __attribute__((ext_vector_type(4))) float;
using u32x2 = __attribute__((ext_vector_type(2))) unsigned int;

static __device__ __forceinline__ float b2f(unsigned short u) {
  union { unsigned int i; float f; } x; x.i = ((unsigned int)u) << 16; return x.f;
}
static __device__ __forceinline__ unsigned short f2b(float f) {
  unsigned int u = __float_as_uint(f);
  u += 0x7fffu + ((u >> 16) & 1u);   // round-to-nearest-even
  return (unsigned short)(u >> 16);
}

#if __has_builtin(__builtin_amdgcn_exp2f)
#define EXP2(x) __builtin_amdgcn_exp2f(x)
#else
#define EXP2(x) exp2f(x)
#endif

// async 16B global -> LDS. LDS dest = wave-uniform base + lane*16 (m104).
typedef const __attribute__((address_space(1))) char gchar;
typedef __attribute__((address_space(3))) char lchar;
static __device__ __forceinline__ void gload_lds16(const void* g, void* l) {
  __builtin_amdgcn_global_load_lds((gchar*)g, (lchar*)l, 16, 0, 0);
}

// ---------------- 1) merged prep: x->bf16 convert + both weight transposes ----
__global__ __launch_bounds__(256) void k_prep(const float* __restrict__ x,
                                              short* __restrict__ xb,
                                              const float* __restrict__ wq,
                                              short* __restrict__ wqT,
                                              const float* __restrict__ wo,
                                              short* __restrict__ woT) {
  __shared__ float tile[32][33];
  const int blk = blockIdx.x;
  const int tid = threadIdx.x;
  if (blk < 4096) {
    const int i = blk * 256 + tid;
    const float4 v = ((const float4*)x)[i];
    s16x4 o;
    o.x = (short)f2b(v.x); o.y = (short)f2b(v.y);
    o.z = (short)f2b(v.z); o.w = (short)f2b(v.w);
    ((s16x4*)xb)[i] = o;
    return;
  }
  const float* in; short* out; int C, bx, by;
  if (blk < 7168) {
    const int l = blk - 4096; in = wq; out = wqT; C = NQKV;
    bx = l % 96; by = l / 96;
  } else {
    const int l = blk - 7168; in = wo; out = woT; C = DMODEL;
    bx = l & 31; by = l >> 5;
  }
  const int tx = tid & 31, ty4 = (tid >> 5) * 4;
#pragma unroll
  for (int i = 0; i < 4; ++i)
    tile[ty4 + i][tx] = in[(by * 32 + ty4 + i) * C + bx * 32 + tx];
  __syncthreads();
#pragma unroll
  for (int i = 0; i < 4; ++i)
    out[(bx * 32 + ty4 + i) * DMODEL + by * 32 + tx] = (short)f2b(tile[tx][ty4 + i]);
}

// ---- 2) fused QKV GEMM: 256^2 tile, 8-wave, 4-phase/K-tile interleave -------
// T3+T4 template (guide 5): per phase {ds_read subtile || stage 1 half-tile ->
// barrier -> lgkmcnt(0) -> setprio(1) -> 16 MFMA -> setprio(0) -> barrier}.
// Counted vmcnt(2) once per K-tile at the publish point (never drains the
// prefetch queue). LDS 128KB: [dbuf][A|B][half][128x64] bf16, XOR-swizzled via
// pre-swizzled gload source. Wave (wr,wc) reads ONLY A-half wr and B-half
// wc>>1 (wave rows/cols stay within one half by construction).
__global__ __launch_bounds__(512, 2) void k_gemm_qkv(const short* __restrict__ A,
                                                     const short* __restrict__ BT,
                                                     short* __restrict__ Qo,
                                                     short* __restrict__ Ko,
                                                     short* __restrict__ Vt) {
  __shared__ __attribute__((aligned(16))) short L[2][2][2][128 * 64];  // 128 KB
  const int K = DMODEL;
  const int tid = threadIdx.x;                 // 0..511
  const int wave = tid >> 6, lane = tid & 63, quad = lane >> 4, l15 = lane & 15;
  const int wr = wave >> 2, wc = wave & 3;     // 2M x 4N wave grid
  const int bid = blockIdx.y * 12 + blockIdx.x;  // 0..191
  const int swz = (bid & 7) * 24 + (bid >> 3);   // XCD-chunked, bijective
  const int bx = swz % 12, by = swz / 12;
  const int m0 = by * 256, n0 = bx * 256;
  f32x4 acc[8][4] = {};
  char* Lb = (char*)L;
  // staging: thread covers chunks i0=tid, i1=512+tid of each 16KB half-tile
  const int r0 = tid >> 3, pc = tid & 7;
  const int sc0 = pc ^ (r0 & 7);
  const int r1 = 64 + r0;
  const int sc1 = pc ^ (r1 & 7);
#define HBASE(buf, ab, h) (Lb + (((buf) * 4 + (ab) * 2 + (h)) * 16384))
#define STAGE_HT(kt1, ab, h)                                                   \
  do {                                                                         \
    const short* src_ = (ab) ? BT : A;                                         \
    const int rowb_ = ((ab) ? n0 : m0) + (h) * 128;                            \
    const long o0_ = ((long)(rowb_ + r0) * K + (kt1) * 64) * 2 + sc0 * 16;     \
    const long o1_ = ((long)(rowb_ + r1) * K + (kt1) * 64) * 2 + sc1 * 16;     \
    char* db_ = HBASE((kt1) & 1, ab, h) + wave * 1024;                         \
    gload_lds16((const char*)src_ + o0_, db_);                                 \
    gload_lds16((const char*)src_ + o1_, db_ + 8192);                          \
  } while (0)

  const int nT = K / 64;  // 16
  // prologue: stage tile 0 fully (4 half-tiles, 8 loads/thread)
  STAGE_HT(0, 0, 0); STAGE_HT(0, 0, 1); STAGE_HT(0, 1, 0); STAGE_HT(0, 1, 1);

  const int rbb = (wc & 1) * 64;               // B row base within its half
  for (int kt = 0; kt < nT; ++kt) {
    const int cur = kt & 1;
    const char* Ah = HBASE(cur, 0, wr);
    const char* Bh = HBASE(cur, 1, wc >> 1);
    s16x8 bf[4][2];
#pragma unroll
    for (int ph = 0; ph < 4; ++ph) {
      s16x8 af[2][2];
      if (ph == 0) {
        // boundary: issue first prefetch, counted wait, publish barrier
        if (kt + 1 < nT) {
          STAGE_HT(kt + 1, 0, 0);
          asm volatile("s_waitcnt vmcnt(2)" ::: "memory");  // tile kt landed
        } else {
          asm volatile("s_waitcnt vmcnt(0)" ::: "memory");
        }
        __builtin_amdgcn_s_barrier();          // publish buf[cur]
        // 12 ds_reads: all B-frags (K-tile-persistent) + A-frags m0,m1
#pragma unroll
        for (int g = 0; g < 4; ++g)
#pragma unroll
          for (int kh = 0; kh < 2; ++kh) {
            const int rb = rbb + g * 16 + l15;
            bf[g][kh] = *(const s16x8*)(Bh + rb * 128 +
                                        (((kh * 4 + quad) ^ (l15 & 7)) * 16));
          }
#pragma unroll
        for (int f2 = 0; f2 < 2; ++f2)
#pragma unroll
          for (int kh = 0; kh < 2; ++kh) {
            const int ra = (ph * 2 + f2) * 16 + l15;
            af[f2][kh] = *(const s16x8*)(Ah + ra * 128 +
                                         (((kh * 4 + quad) ^ (l15 & 7)) * 16));
          }
      } else {
        // ds_reads pre-barrier (overlap), stage one half-tile, then barrier
#pragma unroll
        for (int f2 = 0; f2 < 2; ++f2)
#pragma unroll
          for (int kh = 0; kh < 2; ++kh) {
            const int ra = (ph * 2 + f2) * 16 + l15;
            af[f2][kh] = *(const s16x8*)(Ah + ra * 128 +
                                         (((kh * 4 + quad) ^ (l15 & 7)) * 16));
          }
        if (kt + 1 < nT) {
          if (ph == 1)      STAGE_HT(kt + 1, 0, 1);
          else if (ph == 2) STAGE_HT(kt + 1, 1, 0);
          else              STAGE_HT(kt + 1, 1, 1);
        }
        __builtin_amdgcn_s_barrier();
      }
      asm volatile("s_waitcnt lgkmcnt(0)" ::: "memory");
      __builtin_amdgcn_s_setprio(1);
#pragma unroll
      for (int f2 = 0; f2 < 2; ++f2)
#pragma unroll
        for (int g = 0; g < 4; ++g) {
          acc[ph * 2 + f2][g] = __builtin_amdgcn_mfma_f32_16x16x32_bf16(
              af[f2][0], bf[g][0], acc[ph * 2 + f2][g], 0, 0, 0);
          acc[ph * 2 + f2][g] = __builtin_amdgcn_mfma_f32_16x16x32_bf16(
              af[f2][1], bf[g][1], acc[ph * 2 + f2][g], 0, 0, 0);
        }
      __builtin_amdgcn_s_setprio(0);
      __builtin_amdgcn_s_barrier();            // phase close (reads done)
    }
  }
#undef STAGE_HT
#undef HBASE
  // ---- epilogue: rope-K in-register, then two 64-row passes through the
  // per-wave 8KB LDS transpose scratch -> coalesced 16B stores ----
  const int colhead = n0 + wc * 64;            // one head per wave-column
  const int region = colhead >> 10;            // 0=Q, 1=K, 2=V
  const int hh = (colhead & 1023) >> 6;
  const int bq = m0 >> 11;                     // batch (256-tile never straddles)
  char* sw = Lb + wave * 8192;                 // wave-private scratch (L dead)
  if (region == 1) {
#pragma unroll
    for (int f = 0; f < 8; ++f)
#pragma unroll
      for (int g = 0; g < 2; ++g) {
        const int d = g * 16 + l15;            // 0..31, paired with d+32
        const float inv = exp2f(-(float)d * ROPE_C);
#pragma unroll
        for (int r = 0; r < 4; ++r) {
          const int t = (m0 & 2047) + wr * 128 + f * 16 + quad * 4 + r;
          float sn, cs;
          __sincosf((float)t * inv, &sn, &cs);
          const float a = acc[f][g][r];
          const float bv = acc[f][g + 2][r];
          acc[f][g][r]     = a * cs - bv * sn;
          acc[f][g + 2][r] = bv * cs + a * sn;
        }
      }
  }
#pragma unroll
  for (int P = 0; P < 2; ++P) {
    const int tb = (m0 & 2047) + wr * 128 + P * 64;
    if (region == 2) {
      // V: scratch [d 0..63][t 0..63]; lane's 4 acc values t-contiguous
#pragma unroll
      for (int i2 = 0; i2 < 4; ++i2)
#pragma unroll
        for (int g = 0; g < 4; ++g) {
          const int d = g * 16 + l15;
          const int t0 = i2 * 16 + quad * 4;
          s16x4 w;
          w.x = (short)f2b(acc[P * 4 + i2][g][0]);
          w.y = (short)f2b(acc[P * 4 + i2][g][1]);
          w.z = (short)f2b(acc[P * 4 + i2][g][2]);
          w.w = (short)f2b(acc[P * 4 + i2][g][3]);
          *(s16x4*)(sw + d * 128 + ((((t0 >> 3) ^ (d & 7))) * 16) + (t0 & 7) * 2) = w;
        }
      short* dstv = Vt + (((long)(bq * NHEAD + hh) * HDIM) << 11);
#pragma unroll
      for (int p = 0; p < 8; ++p) {
        const int linear = p * 64 + lane;
        const int d = linear >> 3, c = linear & 7;
        const s16x8 v = *(const s16x8*)(sw + d * 128 + ((c ^ (d & 7)) * 16));
        *(s16x8*)(dstv + (((long)d) << 11) + tb + c * 8) = v;
      }
    } else {
      // Q/K: scratch [t 0..63][d 0..63]
#pragma unroll
      for (int i2 = 0; i2 < 4; ++i2)
#pragma unroll
        for (int g = 0; g < 4; ++g)
#pragma unroll
          for (int r = 0; r < 4; ++r) {
            const int row = i2 * 16 + quad * 4 + r;
            const int col = g * 16 + l15;
            *(short*)(sw + row * 128 + ((((col >> 3) ^ (row & 7))) * 16) + (col & 7) * 2)
                = (short)f2b(acc[P * 4 + i2][g][r]);
          }
      short* dst = (region ? Ko : Qo) + ((long)(bq * NHEAD + hh) * TSEQ + tb) * HDIM;
#pragma unroll
      for (int p = 0; p < 8; ++p) {
        const int linear = p * 64 + lane;
        const int rr = linear >> 3, c = linear & 7;
        const s16x8 v = *(const s16x8*)(sw + rr * 128 + ((c ^ (rr & 7)) * 16));
        *(s16x8*)(dst + (long)rr * HDIM + c * 8) = v;
      }
    }
  }
}

// -- 3) GEMM BMx128, BK=64, LDS dbuf + counted vmcnt (round-7/11 verified) ----
template <int IM, bool OUT_BF16>
__global__ __launch_bounds__(256) void k_gemm(const short* __restrict__ A,
                                              const short* __restrict__ BT,
                                              void* __restrict__ Cv,
                                              int M, int N, int K) {
  static_assert(IM == 2, "vmcnt literal assumes IM==2 (6 loads/thread)");
  __shared__ __attribute__((aligned(16))) short As[2][IM * 32 * 64];
  __shared__ __attribute__((aligned(16))) short Bs[2][128 * 64];
  const int tid = threadIdx.x;
  const int wave = tid >> 6, lane = tid & 63, quad = lane >> 4, l15 = lane & 15;
  const int wm = (wave >> 1) * (IM * 16), wn = (wave & 1) * 64;
  const int nwg = gridDim.x * gridDim.y;
  const int bid = blockIdx.y * gridDim.x + blockIdx.x;
  const int swz = (bid & 7) * (nwg >> 3) + (bid >> 3);
  const int bx = swz % gridDim.x, by = swz / gridDim.x;
  const int m0 = by * (IM * 32), n0 = bx * 128;
  f32x4 acc[IM][4] = {};
  const char* Ab = (const char*)A;
  const char* Bb = (const char*)BT;
  char* AsB = (char*)As;
  char* BsB = (char*)Bs;
  int srow[4], sg[4];
#pragma unroll
  for (int p = 0; p < 4; ++p) {
    const int i = p * 256 + tid;
    srow[p] = i >> 3;
    sg[p] = (i & 7) ^ (srow[p] & 7);
  }
#define GSTAGE(k0v, buf)                                                       \
  do {                                                                         \
    _Pragma("unroll")                                                          \
    for (int p = 0; p < IM; ++p) {                                             \
      const long go = ((long)(m0 + srow[p]) * K + (k0v)) * 2 + sg[p] * 16;     \
      gload_lds16(Ab + go, AsB + (buf) * (IM * 4096) + p * 4096 + wave * 1024);\
    }                                                                          \
    _Pragma("unroll")                                                          \
    for (int p = 0; p < 4; ++p) {                                              \
      const long go = ((long)(n0 + srow[p]) * K + (k0v)) * 2 + sg[p] * 16;     \
      gload_lds16(Bb + go, BsB + (buf) * 16384 + p * 4096 + wave * 1024);      \
    }                                                                          \
  } while (0)

  const int nK = K / 64;
  GSTAGE(0, 0);
  for (int kt = 0; kt < nK; ++kt) {
    const int cur = kt & 1;
    if (kt + 1 < nK) {
      GSTAGE((kt + 1) * 64, cur ^ 1);
      asm volatile("s_waitcnt vmcnt(6)" ::: "memory");  // IM+4 = 6 in flight
    } else {
      asm volatile("s_waitcnt vmcnt(0)" ::: "memory");
    }
    __builtin_amdgcn_s_barrier();
    const char* Ac = AsB + cur * (IM * 4096);
    const char* Bc = BsB + cur * 16384;
#pragma unroll
    for (int hf = 0; hf < 2; ++hf) {
      s16x8 af[IM], bf[4];
#pragma unroll
      for (int i = 0; i < IM; ++i) {
        const int rowa = wm + i * 16 + l15;
        af[i] = *(const s16x8*)(Ac + rowa * 128 + (((hf * 4 + quad) ^ (rowa & 7)) * 16));
      }
#pragma unroll
      for (int j = 0; j < 4; ++j) {
        const int rowb = wn + j * 16 + l15;
        bf[j] = *(const s16x8*)(Bc + rowb * 128 + (((hf * 4 + quad) ^ (rowb & 7)) * 16));
      }
#pragma unroll
      for (int i = 0; i < IM; ++i)
#pragma unroll
        for (int j = 0; j < 4; ++j)
          acc[i][j] = __builtin_amdgcn_mfma_f32_16x16x32_bf16(af[i], bf[j], acc[i][j], 0, 0, 0);
    }
    asm volatile("s_waitcnt lgkmcnt(0)" ::: "memory");
    __builtin_amdgcn_s_barrier();
  }
#undef GSTAGE
  if (OUT_BF16) {
#pragma unroll
    for (int i = 0; i < IM; ++i) {
      const int row = m0 + wm + i * 16 + quad * 4;
#pragma unroll
      for (int j = 0; j < 4; ++j) {
        const int col = n0 + wn + j * 16 + l15;
#pragma unroll
        for (int r = 0; r < 4; ++r)
          ((short*)Cv)[(long)(row + r) * N + col] = (short)f2b(acc[i][j][r]);
      }
    }
  } else {
    // f32 epilogue via per-wave 8KB LDS scratch [32 r][64 c], coalesced stores
    char* sw = (char*)Bs + wave * 8192;   // Bs dead after final barrier
#pragma unroll
    for (int i = 0; i < IM; ++i)
#pragma unroll
      for (int j = 0; j < 4; ++j)
#pragma unroll
        for (int r = 0; r < 4; ++r) {
          const int row = i * 16 + quad * 4 + r;   // 0..31
          const int col = j * 16 + l15;            // 0..63
          *(float*)(sw + row * 256 + ((((col >> 2) ^ (row & 7))) * 16) + (col & 3) * 4)
              = acc[i][j][r];
        }
    float* C = (float*)Cv;
#pragma unroll
    for (int p = 0; p < 8; ++p) {
      const int linear = p * 64 + lane;
      const int r = linear >> 4, c = linear & 15;
      const f32x4 v = *(const f32x4*)(sw + r * 256 + ((c ^ (r & 7)) * 16));
      *(f32x4*)(C + (long)(m0 + wm + r) * N + n0 + wn + c * 4) = v;
    }
  }
}

// ---------------- 4) flash attention v4 (round-4/7/11 verified local optimum):
// BQ=128, 8 waves x 16 q-rows, LDS dbuf + counted vmcnt(2), ones-MFMA row-sum,
// raw v_exp_f32, setprio around MFMA, rope-K pre-applied by k_gemm_qkv.
__global__ __launch_bounds__(512) __attribute__((amdgpu_waves_per_eu(4)))
void k_attn(const short* __restrict__ Qg,
            const short* __restrict__ Kg,
            const short* __restrict__ Vg,
            short* __restrict__ O) {
  __shared__ __attribute__((aligned(16))) short Ks[2][64 * 64];
  __shared__ __attribute__((aligned(16))) short Vs[2][64 * 64];
  __shared__ __attribute__((aligned(16))) short pl[8][16 * 64];  // XOR-swizzled [q][t]
  const int bx = blockIdx.x, by = blockIdx.y;
  const int qi = ((by >> 4) & 1) ? (15 - bx) : bx;
  const int bh = by;
  const int b = bh >> 4, h = bh & 15;
  const int tid = threadIdx.x, wave = tid >> 6, lane = tid & 63;
  const int quad = lane >> 4, l15 = lane & 15;
  const char* Kb = (const char*)(Kg + (long)bh * TSEQ * HDIM);
  const char* Vb = (const char*)(Vg + (long)bh * HDIM * TSEQ);
  const short* Qb = Qg + (long)bh * TSEQ * HDIM;
  const int qr0 = qi * 128 + wave * 16;
  const s16x8 rq0 = *(const s16x8*)&Qb[(qr0 + l15) * HDIM + quad * 8];
  const s16x8 rq1 = *(const s16x8*)&Qb[(qr0 + l15) * HDIM + 32 + quad * 8];
  s16x8 aq0, aq1;
  {
    const float tf = (float)(qr0 + l15);
#pragma unroll
    for (int j = 0; j < 8; ++j) {
      const float inv = exp2f(-(float)(quad * 8 + j) * ROPE_C);
      float sn, cs;
      __sincosf(tf * inv, &sn, &cs);
      sn *= QSCALE; cs *= QSCALE;
      const float q0 = b2f((unsigned short)rq0[j]);
      const float q1 = b2f((unsigned short)rq1[j]);
      aq0[j] = (short)f2b(q0 * cs - q1 * sn);
      aq1[j] = (short)f2b(q1 * cs + q0 * sn);
    }
  }
  s16x8 ones;
#pragma unroll
  for (int j = 0; j < 8; ++j) ones[j] = (short)0x3F80;  // bf16 1.0
  f32x4 o[4] = {};          // O^T: d = hs*16 + quad*4 + r, q = l15
  f32x4 zs = {};            // ones-MFMA row-sum accumulator (cols = q = l15)
  const int kr0 = tid >> 3, kg0 = (tid & 7) ^ (kr0 & 7);
  char* KsB = (char*)Ks;
  char* VsB = (char*)Vs;
  char* plwB = (char*)pl + wave * 2048;
  const int ldsw = wave * 1024;  // + lane*16 by HW

#define STAGE(kjv, buf)                                                     \
  do {                                                                      \
    gload_lds16(Kb + (kjv) * 8192 + (kr0 * 8 + kg0) * 16,                   \
                KsB + (buf) * 8192 + ldsw);                                 \
    gload_lds16(Vb + (kjv) * 128 + kr0 * (TSEQ * 2) + kg0 * 16,             \
                VsB + (buf) * 8192 + ldsw);                                 \
  } while (0)

  STAGE(0, 0);

  const int kjmax = 2 * qi + 1;      // last K-tile this block needs
  const int kjd = qr0 >> 6;          // this wave's diagonal tile (skip beyond)
  for (int kj = 0; kj <= kjmax; ++kj) {
    const int cur = kj & 1;
    if (kj < kjmax) {
      STAGE(kj + 1, cur ^ 1);
      asm volatile("s_waitcnt vmcnt(2)" ::: "memory");
    } else {
      asm volatile("s_waitcnt vmcnt(0)" ::: "memory");
    }
    __builtin_amdgcn_s_barrier();    // publish buf[cur]
    if (kj <= kjd) {
      const char* kb = KsB + cur * 8192;
      const char* vb = VsB + cur * 8192;
      f32x4 s[4];
      __builtin_amdgcn_s_setprio(1);
#pragma unroll
      for (int j2 = 0; j2 < 4; ++j2) {
        const int row = j2 * 16 + l15;
        const s16x8 k0 = *(const s16x8*)(kb + row * 128 + ((quad ^ (row & 7)) * 16));
        const s16x8 k1 = *(const s16x8*)(kb + row * 128 + (((4 + quad) ^ (row & 7)) * 16));
        f32x4 z = {};
        z = __builtin_amdgcn_mfma_f32_16x16x32_bf16(k0, aq0, z, 0, 0, 0);
        z = __builtin_amdgcn_mfma_f32_16x16x32_bf16(k1, aq1, z, 0, 0, 0);
        s[j2] = z;
      }
      __builtin_amdgcn_s_setprio(0);
      if (kj == kjd) {
        const int qloc = (qr0 & 63) + l15;
#pragma unroll
        for (int j2 = 0; j2 < 4; ++j2)
#pragma unroll
          for (int r = 0; r < 4; ++r)
            if (j2 * 16 + quad * 4 + r > qloc) s[j2][r] = NEGINF;
      }
#pragma unroll
      for (int j2 = 0; j2 < 4; ++j2) {
        const unsigned int u0 = __float_as_uint(EXP2(s[j2][0])) & 0xffff0000u;
        const unsigned int u1 = __float_as_uint(EXP2(s[j2][1])) & 0xffff0000u;
        const unsigned int u2 = __float_as_uint(EXP2(s[j2][2])) & 0xffff0000u;
        const unsigned int u3 = __float_as_uint(EXP2(s[j2][3])) & 0xffff0000u;
        u32x2 w;
        w.x = (u0 >> 16) | u1;
        w.y = (u2 >> 16) | u3;
        const int t0 = j2 * 16 + quad * 4;
        *(u32x2*)(plwB + l15 * 128 + (((t0 >> 3) ^ (l15 & 7)) * 16) + (quad & 1) * 8) = w;
      }
      const s16x8 bp0 = *(const s16x8*)(plwB + l15 * 128 + ((quad ^ (l15 & 7)) * 16));
      const s16x8 bp1 = *(const s16x8*)(plwB + l15 * 128 + (((4 + quad) ^ (l15 & 7)) * 16));
      __builtin_amdgcn_s_setprio(1);
      zs = __builtin_amdgcn_mfma_f32_16x16x32_bf16(ones, bp0, zs, 0, 0, 0);
      zs = __builtin_amdgcn_mfma_f32_16x16x32_bf16(ones, bp1, zs, 0, 0, 0);
#pragma unroll
      for (int hs = 0; hs < 4; ++hs) {
        const int d = hs * 16 + l15;
        const s16x8 av0 = *(const s16x8*)(vb + d * 128 + ((quad ^ (d & 7)) * 16));
        const s16x8 av1 = *(const s16x8*)(vb + d * 128 + (((4 + quad) ^ (d & 7)) * 16));
        o[hs] = __builtin_amdgcn_mfma_f32_16x16x32_bf16(av0, bp0, o[hs], 0, 0, 0);
        o[hs] = __builtin_amdgcn_mfma_f32_16x16x32_bf16(av1, bp1, o[hs], 0, 0, 0);
      }
      __builtin_amdgcn_s_setprio(0);
    }
    asm volatile("s_waitcnt lgkmcnt(0)" ::: "memory");
    __builtin_amdgcn_s_barrier();    // all reads of buf[cur] done
  }
#undef STAGE
  const float rinv = 1.0f / zs[0];   // all 4 rows identical = sum_t P[q=l15][t]
  const int t = qr0 + l15;
  short* Orow = O + (long)(b * TSEQ + t) * DMODEL + h * HDIM + quad * 4;
#pragma unroll
  for (int hs = 0; hs < 4; ++hs) {
    s16x4 w;
    w.x = (short)f2b(o[hs][0] * rinv);
    w.y = (short)f2b(o[hs][1] * rinv);
    w.z = (short)f2b(o[hs][2] * rinv);
    w.w = (short)f2b(o[hs][3] * rinv);
    *(s16x4*)(Orow + hs * 16) = w;  // 8B store, d consecutive
  }
}

// ---------------- launch ----------------
extern "C" void kernel_launch(void* const* d_in, const int* in_sizes, int n_in,
                              void* d_out, int out_size, void* d_ws, size_t ws_size,
                              hipStream_t stream) {
  const float* x = (const float*)d_in[0];      // [2,2048,1024]
  const float* w_qkv = (const float*)d_in[1];  // [1024,3072]
  const float* w_out = (const float*)d_in[2];  // [1024,1024]
  float* out = (float*)d_out;                  // [2,2048,1024]
  char* ws = (char*)d_ws;

  short* xb    = (short*)(ws);                        //  8 MiB
  short* wqkvT = (short*)(ws + (8ll << 20));          //  6 MiB
  short* woutT = (short*)(ws + (14ll << 20));         //  2 MiB
  short* Qb    = (short*)(ws + (16ll << 20));         //  8 MiB
  short* Kb    = (short*)(ws + (24ll << 20));         //  8 MiB
  short* Vt    = (short*)(ws + (32ll << 20));         //  8 MiB
  short* Ob    = (short*)(ws + (40ll << 20));         //  8 MiB  (total 48 MiB)

  k_prep<<<dim3(8192), dim3(256), 0, stream>>>(x, xb, w_qkv, wqkvT, w_out, woutT);
  k_gemm_qkv<<<dim3(NQKV / 256, MROWS / 256), dim3(512), 0, stream>>>(
      xb, wqkvT, Qb, Kb, Vt);
  k_attn<<<dim3(TSEQ / 128, NB * NHEAD), dim3(512), 0, stream>>>(Qb, Kb, Vt, Ob);
  k_gemm<2, false><<<dim3(DMODEL / 128, MROWS / 64), dim3(256), 0, stream>>>(
      Ob, woutT, (void*)out, MROWS, DMODEL, DMODEL);
}